// Round 1
// 7593.788 us; speedup vs baseline: 1.1754x; 1.1754x over previous
//
#include <hip/hip_runtime.h>
#include <hip/hip_bf16.h>

// LSTM: N=64, T=1024, D=512, H=512. out (N,T,H) fp32 = h_{t+1} for t=0..T-1.
//
// Design: persistent kernel, 128 wgs x 256 thr (one per CU, all resident).
//   grid = 32 col-groups (16 h-cols each) x 4 row-groups (16 batch rows each).
//   Each wave (4/wg) owns one gate's 16 a-cols, K=1024 ([x_t | h_t]) with
//   fp16 B-fragments persistent in 128 VGPRs. A staged to LDS per step.
//   Row-groups are independent sync domains (32 wgs each).
//
// R1 change (fence elimination): the h handoff no longer uses full
//   __threadfence() (= buffer_wbl2 + buffer_inv per wg per step, which
//   invalidated the whole per-XCD L2 and forced HBM refetch of x/h).
//   Instead:
//     - h ring stores:  __hip_atomic_store  (agent scope, sc-flagged
//       write-through -> visible at coherence point, no wbl2 needed)
//     - h ring loads:   __hip_atomic_load 64-bit (agent scope, bypasses
//       stale L2 -> no buffer_inv needed)
//     - arrival:        __hip_atomic_fetch_add RELEASE agent (single wbl2
//       of the small dirty set, ordered after __syncthreads' vmcnt(0))
//     - spin:           relaxed agent load + s_sleep backoff (acquire would
//       re-emit buffer_inv; unnecessary since data loads are coherent)

#define TT 1024
#define NB 64
#define DD 512
#define HH 512
#define LROW 1032  // 1024 K elems + 8 pad (breaks power-of-2 LDS stride)

typedef _Float16 half8 __attribute__((ext_vector_type(8)));
typedef _Float16 half4 __attribute__((ext_vector_type(4)));
typedef float floatx4 __attribute__((ext_vector_type(4)));

__global__ void init_ws_kernel(int* done) {
    done[threadIdx.x] = 0;  // 256 ints covers 4 row-group counters (stride 64)
}

__global__ __launch_bounds__(256, 1) void lstm_persist(
    const float* __restrict__ x, const float* __restrict__ h0,
    const float* __restrict__ Wx, const float* __restrict__ Wh,
    const float* __restrict__ b, float* __restrict__ out,
    _Float16* __restrict__ hbuf, int* __restrict__ done)
{
    const int tid  = threadIdx.x;
    const int lane = tid & 63;
    const int wave = tid >> 6;          // 0..3 = gate (i,f,o,g)
    const int cg   = blockIdx.x & 31;   // column group: h-cols cg*16..+15
    const int rg   = blockIdx.x >> 5;   // row group: batch rows rg*16..+15
    const int row0 = rg << 4;

    __shared__ _Float16 xh[16 * LROW];     // A tile: 16 rows x (512 x | 512 h)
    __shared__ float    gatebuf[4 * 272];  // 4 gates x (16 rows x 17 padded)

    // ---- persistent B fragments: this wave's 16 a-cols, full K=1024 ----
    // B[k][n]: n = lane&15, k = kt*32 + (lane>>4)*8 + j
    const int bcol = (wave << 9) + (cg << 4) + (lane & 15);
    const int kq   = (lane >> 4) << 3;
    half8 bfrag[32];
#pragma unroll
    for (int kt = 0; kt < 16; ++kt) {      // K 0..511 : Wx
#pragma unroll
        for (int j = 0; j < 8; ++j) {
            int k = (kt << 5) + kq + j;
            bfrag[kt][j] = (_Float16)Wx[(size_t)k * 2048 + bcol];
        }
    }
#pragma unroll
    for (int kt = 16; kt < 32; ++kt) {     // K 512..1023 : Wh
#pragma unroll
        for (int j = 0; j < 8; ++j) {
            int k = (kt << 5) + kq + j - 512;
            bfrag[kt][j] = (_Float16)Wh[(size_t)k * 2048 + bcol];
        }
    }

    // ---- epilogue mapping: thread <-> (row, col) of the 16x16 h tile ----
    const int tr = tid >> 4;
    const int tc = tid & 15;
    const int gn = row0 + tr;         // global batch row
    const int gh = (cg << 4) + tc;    // global h col
    const float bi = b[0 * 512 + gh];
    const float bf = b[1 * 512 + gh];
    const float bo = b[2 * 512 + gh];
    const float bg = b[3 * 512 + gh];
    float c_state = 0.f;

    int* dptr = done + (rg << 6);     // 256B-spaced counter per row-group

    const int r2 = tid >> 7;          // 0..1 : row parity for staging
    const int d4 = tid & 127;         // vec4 index within a 512-elem row
    const int arow = (lane & 15) * LROW + kq;   // A-frag base (elems)

    for (int t = 0; t < TT; ++t) {
        // ---- stage x_t rows (K 0..511), fp32 -> fp16 (independent of h) ----
#pragma unroll
        for (int i = 0; i < 8; ++i) {
            int r = (i << 1) + r2;
            const float* xrow = x + (size_t)(row0 + r) * (TT * DD) + (size_t)t * DD;
            float4 xv = ((const float4*)xrow)[d4];
            half4 hv;
            hv.x = (_Float16)xv.x; hv.y = (_Float16)xv.y;
            hv.z = (_Float16)xv.z; hv.w = (_Float16)xv.w;
            *(half4*)&xh[r * LROW + (d4 << 2)] = hv;
        }

        // ---- wait for h_t (all 32 wgs of this row-group done with step t-1) ----
        if (t > 0) {
            if (tid == 0) {
                const int target = t << 5;
                while (__hip_atomic_load(dptr, __ATOMIC_RELAXED,
                                         __HIP_MEMORY_SCOPE_AGENT) < target) {
                    __builtin_amdgcn_s_sleep(1);
                }
            }
            __syncthreads();
            // ---- stage h_t rows (K 512..1023) from ring buffer ----
            // agent-scope 64-bit loads: served from coherence point (no L2
            // invalidate needed; cannot hit stale lines)
            unsigned long long* hsrc64 = (unsigned long long*)
                (hbuf + (size_t)(t & 1) * (NB * HH));
#pragma unroll
            for (int i = 0; i < 8; ++i) {
                int r = (i << 1) + r2;
                unsigned long long hv8 = __hip_atomic_load(
                    hsrc64 + (size_t)(row0 + r) * (HH / 4) + d4,
                    __ATOMIC_RELAXED, __HIP_MEMORY_SCOPE_AGENT);
                *(unsigned long long*)&xh[r * LROW + 512 + (d4 << 2)] = hv8;
            }
        } else {
            // h_0 from input (fp32 -> fp16)
#pragma unroll
            for (int i = 0; i < 8; ++i) {
                int r = (i << 1) + r2;
                const float* hrow = h0 + (size_t)(row0 + r) * HH;
                float4 xv = ((const float4*)hrow)[d4];
                half4 hv;
                hv.x = (_Float16)xv.x; hv.y = (_Float16)xv.y;
                hv.z = (_Float16)xv.z; hv.w = (_Float16)xv.w;
                *(half4*)&xh[r * LROW + 512 + (d4 << 2)] = hv;
            }
        }
        __syncthreads();

        // ---- MFMA: 16 rows x 16 cols, K=1024, two independent chains ----
        floatx4 acc0 = {0.f, 0.f, 0.f, 0.f};
        floatx4 acc1 = {0.f, 0.f, 0.f, 0.f};
#pragma unroll
        for (int kt = 0; kt < 32; kt += 2) {
            half8 a0 = *(const half8*)&xh[arow + (kt << 5)];
            half8 a1 = *(const half8*)&xh[arow + ((kt + 1) << 5)];
            acc0 = __builtin_amdgcn_mfma_f32_16x16x32_f16(a0, bfrag[kt],     acc0, 0, 0, 0);
            acc1 = __builtin_amdgcn_mfma_f32_16x16x32_f16(a1, bfrag[kt + 1], acc1, 0, 0, 0);
        }
        floatx4 acc = acc0 + acc1;

        // ---- exchange gates through LDS: C/D layout col=lane&15, row=quad*4+v ----
        {
            const int ccol = lane & 15;
            const int crow = (lane >> 4) << 2;
#pragma unroll
            for (int v = 0; v < 4; ++v)
                gatebuf[wave * 272 + (crow + v) * 17 + ccol] = acc[v];
        }
        __syncthreads();

        // ---- elementwise LSTM cell, write out (fp32) + h ring (fp16, coherent) ----
        {
            const int gidx = tr * 17 + tc;
            float ai = gatebuf[0 * 272 + gidx] + bi;
            float af = gatebuf[1 * 272 + gidx] + bf;
            float ao = gatebuf[2 * 272 + gidx] + bo;
            float ag = gatebuf[3 * 272 + gidx] + bg;
            float ig = 1.f / (1.f + __expf(-ai));
            float fg = 1.f / (1.f + __expf(-af));
            float og = 1.f / (1.f + __expf(-ao));
            float gg = 2.f / (1.f + __expf(-2.f * ag)) - 1.f;   // tanh
            c_state = fg * c_state + ig * gg;
            float hv = og * (2.f / (1.f + __expf(-2.f * c_state)) - 1.f);
            out[(size_t)gn * (TT * HH) + (size_t)t * HH + gh] = hv;
            _Float16 hh = (_Float16)hv;
            unsigned short hu;
            __builtin_memcpy(&hu, &hh, sizeof(hu));
            __hip_atomic_store(
                (unsigned short*)(hbuf + (size_t)((t + 1) & 1) * (NB * HH)
                                  + (size_t)gn * HH + gh),
                hu, __ATOMIC_RELAXED, __HIP_MEMORY_SCOPE_AGENT);
        }

        // ---- arrive: __syncthreads drains vmcnt(0) (all agent-scope h stores
        //      at coherence point); RELEASE fetch_add orders + publishes ----
        __syncthreads();
        if (tid == 0) {
            __hip_atomic_fetch_add(dptr, 1, __ATOMIC_RELEASE,
                                   __HIP_MEMORY_SCOPE_AGENT);
        }
    }
}

extern "C" void kernel_launch(void* const* d_in, const int* in_sizes, int n_in,
                              void* d_out, int out_size, void* d_ws, size_t ws_size,
                              hipStream_t stream) {
    const float* x  = (const float*)d_in[0];
    const float* h0 = (const float*)d_in[1];
    const float* Wx = (const float*)d_in[2];
    const float* Wh = (const float*)d_in[3];
    const float* b  = (const float*)d_in[4];
    float* out = (float*)d_out;

    _Float16* hbuf = (_Float16*)d_ws;                       // 2*64*512 fp16 = 128 KB
    int* done = (int*)((char*)d_ws + 2 * NB * HH * sizeof(_Float16));

    init_ws_kernel<<<1, 256, 0, stream>>>(done);
    lstm_persist<<<dim3(128), dim3(256), 0, stream>>>(x, h0, Wx, Wh, b, out, hbuf, done);
}

// Round 2
// 6989.198 us; speedup vs baseline: 1.2771x; 1.0865x over previous
//
#include <hip/hip_runtime.h>
#include <hip/hip_bf16.h>

// LSTM: N=64, T=1024, D=512, H=512. out (N,T,H) fp32 = h_{t+1} for t=0..T-1.
//
// Design: persistent kernel, 128 wgs x 256 thr (one per CU, all resident).
//   grid = 32 col-groups (16 h-cols each) x 4 row-groups (16 batch rows each).
//   Each wave (4/wg) owns one gate's 16 a-cols, K=1024 ([x_t | h_t]) with
//   fp16 B-fragments persistent in 128 VGPRs. Row-groups are independent
//   sync domains (32 wgs each), communicating h through a fp16 ring buffer
//   at agent scope (coherence-point loads/stores, no full threadfence).
//
// R2 changes (critical-path restructure; handoff was ~7.4us/step):
//   1. x double-buffered in LDS: x_{t+1} global loads issued right after the
//      h-MFMAs, converted+written to the alternate LDS x-half after the
//      epilogue. Top-of-loop no longer exposes an x load round trip.
//   2. Per-cg flag lines (32 x 64B per row-group) replace the contended
//      single atomicAdd counter: producers publish independently (RELEASE
//      store), consumer polls all 32 flags with lanes 0..31 in parallel.
//   3. x-part MFMAs (kt 0..15) computed BEFORE the flag wait (independent
//      of h); only h-part MFMAs (kt 16..31) + epilogue remain after arrival.
//   4. out (HBM) store moved after the flag publication - its write-ack is
//      off the release path.

#define TT 1024
#define NB 64
#define DD 512
#define HH 512
#define XROW 520  // 512 elems + 8 pad (stride 1040B = 260 dw; 260%32=4 -> 2-way max)

typedef _Float16 half8 __attribute__((ext_vector_type(8)));
typedef _Float16 half4 __attribute__((ext_vector_type(4)));
typedef float floatx4 __attribute__((ext_vector_type(4)));

__global__ void init_ws_kernel(int* done) {
    done[blockIdx.x * 256 + threadIdx.x] = 0;  // 2048 ints: 4 rgs x 32 flags x 16-int pad
}

__global__ __launch_bounds__(256, 1) void lstm_persist(
    const float* __restrict__ x, const float* __restrict__ h0,
    const float* __restrict__ Wx, const float* __restrict__ Wh,
    const float* __restrict__ b, float* __restrict__ out,
    _Float16* __restrict__ hbuf, int* __restrict__ done)
{
    const int tid  = threadIdx.x;
    const int lane = tid & 63;
    const int wave = tid >> 6;          // 0..3 = gate (i,f,o,g)
    const int cg   = blockIdx.x & 31;   // column group: h-cols cg*16..+15
    const int rg   = blockIdx.x >> 5;   // row group: batch rows rg*16..+15
    const int row0 = rg << 4;

    __shared__ _Float16 xbuf[2][16 * XROW];   // x_t / x_{t+1} A-halves (K 0..511)
    __shared__ _Float16 hbufL[16 * XROW];     // h_t A-half (K 512..1023)
    __shared__ float    gatebuf[4 * 272];     // 4 gates x (16 rows x 17 padded)

    // ---- persistent B fragments: this wave's 16 a-cols, full K=1024 ----
    // B[k][n]: n = lane&15, k = kt*32 + (lane>>4)*8 + j
    const int bcol = (wave << 9) + (cg << 4) + (lane & 15);
    const int kq   = (lane >> 4) << 3;
    half8 bfrag[32];
#pragma unroll
    for (int kt = 0; kt < 16; ++kt) {      // K 0..511 : Wx
#pragma unroll
        for (int j = 0; j < 8; ++j) {
            int k = (kt << 5) + kq + j;
            bfrag[kt][j] = (_Float16)Wx[(size_t)k * 2048 + bcol];
        }
    }
#pragma unroll
    for (int kt = 16; kt < 32; ++kt) {     // K 512..1023 : Wh
#pragma unroll
        for (int j = 0; j < 8; ++j) {
            int k = (kt << 5) + kq + j - 512;
            bfrag[kt][j] = (_Float16)Wh[(size_t)k * 2048 + bcol];
        }
    }

    // ---- epilogue mapping: thread <-> (row, col) of the 16x16 h tile ----
    const int tr = tid >> 4;
    const int tc = tid & 15;
    const int gn = row0 + tr;         // global batch row
    const int gh = (cg << 4) + tc;    // global h col
    const float bi = b[0 * 512 + gh];
    const float bf = b[1 * 512 + gh];
    const float bo = b[2 * 512 + gh];
    const float bg = b[3 * 512 + gh];
    float c_state = 0.f;

    int* flags  = done + (rg << 9);   // this rg's 32 flag lines (16 ints apart)
    int* myflag = flags + (cg << 4);

    const int r2 = tid >> 7;          // 0..1 : row parity for staging
    const int d4 = tid & 127;         // vec4 index within a 512-elem row
    const int arow = (lane & 15) * XROW + kq;   // A-frag base (elems)

    // ---- prologue: stage x_0 and h_0 ----
#pragma unroll
    for (int i = 0; i < 8; ++i) {
        int r = (i << 1) + r2;
        float4 xv = ((const float4*)(x + (size_t)(row0 + r) * (TT * DD)))[d4];
        half4 hv;
        hv.x = (_Float16)xv.x; hv.y = (_Float16)xv.y;
        hv.z = (_Float16)xv.z; hv.w = (_Float16)xv.w;
        *(half4*)&xbuf[0][r * XROW + (d4 << 2)] = hv;
        float4 h4 = ((const float4*)(h0 + (size_t)(row0 + r) * HH))[d4];
        half4 hh;
        hh.x = (_Float16)h4.x; hh.y = (_Float16)h4.y;
        hh.z = (_Float16)h4.z; hh.w = (_Float16)h4.w;
        *(half4*)&hbufL[r * XROW + (d4 << 2)] = hh;
    }
    __syncthreads();

    for (int t = 0; t < TT; ++t) {
        // ---- 1. x-part MFMA (kt 0..15), independent of h_t ----
        floatx4 acc0 = {0.f, 0.f, 0.f, 0.f};
        floatx4 acc1 = {0.f, 0.f, 0.f, 0.f};
        const _Float16* xa = xbuf[t & 1];
#pragma unroll
        for (int kt = 0; kt < 16; kt += 2) {
            half8 a0 = *(const half8*)&xa[arow + (kt << 5)];
            half8 a1 = *(const half8*)&xa[arow + ((kt + 1) << 5)];
            acc0 = __builtin_amdgcn_mfma_f32_16x16x32_f16(a0, bfrag[kt],     acc0, 0, 0, 0);
            acc1 = __builtin_amdgcn_mfma_f32_16x16x32_f16(a1, bfrag[kt + 1], acc1, 0, 0, 0);
        }

        if (t > 0) {
            // ---- 2. wait: poll all 32 per-cg flags with lanes 0..31 ----
            if (lane < 32) {
                int* fp = flags + (lane << 4);
                int v = __hip_atomic_load(fp, __ATOMIC_RELAXED,
                                          __HIP_MEMORY_SCOPE_AGENT);
                while (v < t) {
                    __builtin_amdgcn_s_sleep(1);
                    v = __hip_atomic_load(fp, __ATOMIC_RELAXED,
                                          __HIP_MEMORY_SCOPE_AGENT);
                }
            }
            asm volatile("" ::: "memory");  // compiler fence: no hoist above poll

            // ---- 3. stage h_t from ring (agent loads: coherence-point) ----
            const unsigned long long* hsrc64 = (const unsigned long long*)
                (hbuf + (size_t)(t & 1) * (NB * HH));
#pragma unroll
            for (int i = 0; i < 8; ++i) {
                int r = (i << 1) + r2;
                unsigned long long hv8 = __hip_atomic_load(
                    hsrc64 + (size_t)(row0 + r) * (HH / 4) + d4,
                    __ATOMIC_RELAXED, __HIP_MEMORY_SCOPE_AGENT);
                *(unsigned long long*)&hbufL[r * XROW + (d4 << 2)] = hv8;
            }
        }
        __syncthreads();   // (A) h tile visible to all waves

        // ---- 5. h-part MFMA (kt 16..31) ----
#pragma unroll
        for (int kt = 0; kt < 16; kt += 2) {
            half8 a0 = *(const half8*)&hbufL[arow + (kt << 5)];
            half8 a1 = *(const half8*)&hbufL[arow + ((kt + 1) << 5)];
            acc0 = __builtin_amdgcn_mfma_f32_16x16x32_f16(a0, bfrag[16 + kt],     acc0, 0, 0, 0);
            acc1 = __builtin_amdgcn_mfma_f32_16x16x32_f16(a1, bfrag[16 + kt + 1], acc1, 0, 0, 0);
        }
        floatx4 acc = acc0 + acc1;

        // ---- 6. issue x_{t+1} global loads (in flight through epilogue) ----
        float4 xv0, xv1, xv2, xv3, xv4, xv5, xv6, xv7;
        const bool havex = (t + 1 < TT);
        if (havex) {
            const float* xb = x + (size_t)(t + 1) * DD;
            xv0 = ((const float4*)(xb + (size_t)(row0 + 0 + r2) * (TT * DD)))[d4];
            xv1 = ((const float4*)(xb + (size_t)(row0 + 2 + r2) * (TT * DD)))[d4];
            xv2 = ((const float4*)(xb + (size_t)(row0 + 4 + r2) * (TT * DD)))[d4];
            xv3 = ((const float4*)(xb + (size_t)(row0 + 6 + r2) * (TT * DD)))[d4];
            xv4 = ((const float4*)(xb + (size_t)(row0 + 8 + r2) * (TT * DD)))[d4];
            xv5 = ((const float4*)(xb + (size_t)(row0 + 10 + r2) * (TT * DD)))[d4];
            xv6 = ((const float4*)(xb + (size_t)(row0 + 12 + r2) * (TT * DD)))[d4];
            xv7 = ((const float4*)(xb + (size_t)(row0 + 14 + r2) * (TT * DD)))[d4];
        }

        // ---- 7. exchange gates through LDS: C/D layout col=lane&15, row=quad*4+v ----
        {
            const int ccol = lane & 15;
            const int crow = (lane >> 4) << 2;
#pragma unroll
            for (int v = 0; v < 4; ++v)
                gatebuf[wave * 272 + (crow + v) * 17 + ccol] = acc[v];
        }
        __syncthreads();   // (B)

        // ---- 8. elementwise LSTM cell; h ring store (agent, write-through) ----
        float hv;
        {
            const int gidx = tr * 17 + tc;
            float ai = gatebuf[0 * 272 + gidx] + bi;
            float af = gatebuf[1 * 272 + gidx] + bf;
            float ao = gatebuf[2 * 272 + gidx] + bo;
            float ag = gatebuf[3 * 272 + gidx] + bg;
            float ig = 1.f / (1.f + __expf(-ai));
            float fg = 1.f / (1.f + __expf(-af));
            float og = 1.f / (1.f + __expf(-ao));
            float gg = 2.f / (1.f + __expf(-2.f * ag)) - 1.f;   // tanh
            c_state = fg * c_state + ig * gg;
            hv = og * (2.f / (1.f + __expf(-2.f * c_state)) - 1.f);
            _Float16 hh = (_Float16)hv;
            unsigned short hu;
            __builtin_memcpy(&hu, &hh, sizeof(hu));
            __hip_atomic_store(
                (unsigned short*)(hbuf + (size_t)((t + 1) & 1) * (NB * HH)
                                  + (size_t)gn * HH + gh),
                hu, __ATOMIC_RELAXED, __HIP_MEMORY_SCOPE_AGENT);
        }

        // ---- 9. convert + write x_{t+1} into alternate LDS x-half ----
        if (havex) {
            _Float16* xd = (_Float16*)xbuf[(t + 1) & 1];
            half4 hc;
#pragma unroll
            for (int i = 0; i < 8; ++i) {
                float4 v;
                switch (i) {
                    case 0: v = xv0; break; case 1: v = xv1; break;
                    case 2: v = xv2; break; case 3: v = xv3; break;
                    case 4: v = xv4; break; case 5: v = xv5; break;
                    case 6: v = xv6; break; default: v = xv7; break;
                }
                hc.x = (_Float16)v.x; hc.y = (_Float16)v.y;
                hc.z = (_Float16)v.z; hc.w = (_Float16)v.w;
                *(half4*)&xd[((i << 1) + r2) * XROW + (d4 << 2)] = hc;
            }
        }

        // ---- 10. drain (each wave waits vmcnt(0) before s_barrier) ----
        __syncthreads();   // (C) h stores at coherence point; xbuf[(t+1)&1] ready

        // ---- 11. publish; 12. out store off the release path ----
        if (tid == 0) {
            __hip_atomic_store(myflag, t + 1, __ATOMIC_RELEASE,
                               __HIP_MEMORY_SCOPE_AGENT);
        }
        out[(size_t)gn * (TT * HH) + (size_t)t * HH + gh] = hv;
    }
}

extern "C" void kernel_launch(void* const* d_in, const int* in_sizes, int n_in,
                              void* d_out, int out_size, void* d_ws, size_t ws_size,
                              hipStream_t stream) {
    const float* x  = (const float*)d_in[0];
    const float* h0 = (const float*)d_in[1];
    const float* Wx = (const float*)d_in[2];
    const float* Wh = (const float*)d_in[3];
    const float* b  = (const float*)d_in[4];
    float* out = (float*)d_out;

    _Float16* hbuf = (_Float16*)d_ws;                       // 2*64*512 fp16 = 128 KB
    int* done = (int*)((char*)d_ws + 2 * NB * HH * sizeof(_Float16));

    init_ws_kernel<<<8, 256, 0, stream>>>(done);            // zero 2048 flag ints
    lstm_persist<<<dim3(128), dim3(256), 0, stream>>>(x, h0, Wx, Wh, b, out, hbuf, done);
}

// Round 3
// 6753.664 us; speedup vs baseline: 1.3216x; 1.0349x over previous
//
#include <hip/hip_runtime.h>
#include <hip/hip_bf16.h>

// LSTM: N=64, T=1024, D=512, H=512. out (N,T,H) fp32 = h_{t+1} for t=0..T-1.
//
// Persistent kernel, 128 wgs x 256 thr. grid = 32 col-groups x 4 row-groups.
// Each wave owns one gate's 16 a-cols, K=1024, fp16 B persistent in VGPRs.
//
// R3 changes (latency surgery; step was ~6.7us, work is ~0.3us):
//   1. NO __syncthreads in the loop: raw s_barrier + manual s_waitcnt
//      lgkmcnt(0) only. vmcnt is never drained at barriers, so streaming
//      x-loads stop poisoning the release path (in-order vmcnt retire).
//   2. h A-fragments loaded DIRECTLY from the MALL-resident fp16 ring with
//      agent-scope 8B loads (no LDS staging, no barrier between poll and
//      h-MFMA). 4x MALL read traffic, zero HBM delta.
//   3. Per-wave publish: 128 flags/row-group (cg x wave). Each wave does
//      s_waitcnt vmcnt(0) on its OWN h stores then a RELAXED sc1 flag
//      store. No wbl2, no barrier, no tid0 serialization on the path.
//   4. h ring deepened to 3 slots (overwrite margin >= 2 full steps).
//   5. h stores packed 4x fp16 -> one 8B store via 3 intra-row shuffles.
//   6. x_{t+1} loads issued at loop TOP: their HBM latency overlaps the
//      producer wait; retired long before the publish vmcnt(0).

#define TT 1024
#define NB 64
#define DD 512
#define HH 512
#define XROW 520   // 512 + 8 pad
#define NBHH (NB * HH)

typedef _Float16 half8 __attribute__((ext_vector_type(8)));
typedef _Float16 half4 __attribute__((ext_vector_type(4)));
typedef float floatx4 __attribute__((ext_vector_type(4)));
typedef unsigned long long u64;

union H8 { u64 u[2]; half8 h; };

#define AQ __ATOMIC_RELAXED
#define SC __HIP_MEMORY_SCOPE_AGENT

__global__ void init_ws_kernel(int* done) {
    done[blockIdx.x * 256 + threadIdx.x] = -1;   // 8192 ints: 4rg x 128 flags x 16-int pad
}

__device__ __forceinline__ void barrier_lgkm() {
    asm volatile("s_waitcnt lgkmcnt(0)" ::: "memory");
    __builtin_amdgcn_s_barrier();
    asm volatile("" ::: "memory");
}

__global__ __launch_bounds__(256, 1) void lstm_persist(
    const float* __restrict__ x, const float* __restrict__ h0,
    const float* __restrict__ Wx, const float* __restrict__ Wh,
    const float* __restrict__ b, float* __restrict__ out,
    _Float16* __restrict__ hbuf, int* __restrict__ done)
{
    const int tid  = threadIdx.x;
    const int lane = tid & 63;
    const int wave = tid >> 6;          // 0..3 = gate (i,f,o,g)
    const int cg   = blockIdx.x & 31;   // h-cols cg*16..+15
    const int rg   = blockIdx.x >> 5;   // batch rows rg*16..+15
    const int row0 = rg << 4;

    __shared__ _Float16 xbuf[2][16 * XROW];   // x_t / x_{t+1} A-halves
    __shared__ float    gatebuf[4 * 272];     // 4 gates x (16 x 17)

    // ---- persistent B fragments ----
    const int bcol = (wave << 9) + (cg << 4) + (lane & 15);
    const int kq   = (lane >> 4) << 3;
    half8 bfrag[32];
#pragma unroll
    for (int kt = 0; kt < 16; ++kt)
#pragma unroll
        for (int j = 0; j < 8; ++j)
            bfrag[kt][j] = (_Float16)Wx[(size_t)((kt << 5) + kq + j) * 2048 + bcol];
#pragma unroll
    for (int kt = 16; kt < 32; ++kt)
#pragma unroll
        for (int j = 0; j < 8; ++j)
            bfrag[kt][j] = (_Float16)Wh[(size_t)((kt << 5) + kq + j - 512) * 2048 + bcol];

    // ---- epilogue mapping ----
    const int tr = tid >> 4;
    const int tc = tid & 15;
    const int gn = row0 + tr;
    const int gh = (cg << 4) + tc;
    const float bi = b[0 * 512 + gh];
    const float bf = b[1 * 512 + gh];
    const float bo = b[2 * 512 + gh];
    const float bg = b[3 * 512 + gh];
    float c_state = 0.f;

    int* flags  = done + (rg << 11);                       // 128 flags x 16 ints
    int* myflag = flags + (((cg << 2) + wave) << 4);

    const int r2 = tid >> 7;
    const int d4 = tid & 127;
    const int arow = (lane & 15) * XROW + kq;

    // ---- prologue: stage x_0 to LDS; h0 -> ring slot 0 (fp16, packed 8B) ----
#pragma unroll
    for (int i = 0; i < 8; ++i) {
        int r = (i << 1) + r2;
        float4 xv = ((const float4*)(x + (size_t)(row0 + r) * (TT * DD)))[d4];
        half4 hc;
        hc.x = (_Float16)xv.x; hc.y = (_Float16)xv.y;
        hc.z = (_Float16)xv.z; hc.w = (_Float16)xv.w;
        *(half4*)&xbuf[0][r * XROW + (d4 << 2)] = hc;
    }
    {
        float hv = h0[(size_t)gn * HH + gh];
        float n1 = __shfl_down(hv, 1);
        float n2 = __shfl_down(hv, 2);
        float n3 = __shfl_down(hv, 3);
        if ((tc & 3) == 0) {
            _Float16 f0 = (_Float16)hv, f1 = (_Float16)n1,
                     f2 = (_Float16)n2, f3 = (_Float16)n3;
            unsigned short s0, s1, s2, s3;
            __builtin_memcpy(&s0, &f0, 2); __builtin_memcpy(&s1, &f1, 2);
            __builtin_memcpy(&s2, &f2, 2); __builtin_memcpy(&s3, &f3, 2);
            u64 v = (u64)s0 | ((u64)s1 << 16) | ((u64)s2 << 32) | ((u64)s3 << 48);
            __hip_atomic_store((u64*)hbuf + (size_t)gn * 128 + (gh >> 2), v, AQ, SC);
        }
        asm volatile("s_waitcnt vmcnt(0)" ::: "memory");
        if (lane == 0) __hip_atomic_store(myflag, 0, AQ, SC);
    }
    barrier_lgkm();   // xbuf[0] visible

    int sr = 0;   // read slot = t % 3
    for (int t = 0; t < TT; ++t) {
        const int sw = (sr + 1 == 3) ? 0 : sr + 1;   // write slot
        const bool havex = (t + 1 < TT);

        // ---- issue x_{t+1} loads (latency hides under producer wait) ----
        float4 xv0, xv1, xv2, xv3, xv4, xv5, xv6, xv7;
        if (havex) {
            const float* xb = x + (size_t)(t + 1) * DD;
            xv0 = ((const float4*)(xb + (size_t)(row0 + 0  + r2) * (TT * DD)))[d4];
            xv1 = ((const float4*)(xb + (size_t)(row0 + 2  + r2) * (TT * DD)))[d4];
            xv2 = ((const float4*)(xb + (size_t)(row0 + 4  + r2) * (TT * DD)))[d4];
            xv3 = ((const float4*)(xb + (size_t)(row0 + 6  + r2) * (TT * DD)))[d4];
            xv4 = ((const float4*)(xb + (size_t)(row0 + 8  + r2) * (TT * DD)))[d4];
            xv5 = ((const float4*)(xb + (size_t)(row0 + 10 + r2) * (TT * DD)))[d4];
            xv6 = ((const float4*)(xb + (size_t)(row0 + 12 + r2) * (TT * DD)))[d4];
            xv7 = ((const float4*)(xb + (size_t)(row0 + 14 + r2) * (TT * DD)))[d4];
        }

        // ---- x-part MFMA (LDS only, no vm deps) ----
        floatx4 acc0 = {0.f, 0.f, 0.f, 0.f};
        floatx4 acc1 = {0.f, 0.f, 0.f, 0.f};
        const _Float16* xa = xbuf[t & 1];
#pragma unroll
        for (int kt = 0; kt < 16; kt += 2) {
            half8 a0 = *(const half8*)&xa[arow + (kt << 5)];
            half8 a1 = *(const half8*)&xa[arow + ((kt + 1) << 5)];
            acc0 = __builtin_amdgcn_mfma_f32_16x16x32_f16(a0, bfrag[kt],     acc0, 0, 0, 0);
            acc1 = __builtin_amdgcn_mfma_f32_16x16x32_f16(a1, bfrag[kt + 1], acc1, 0, 0, 0);
        }

        // ---- poll: 128 per-(cg,wave) flags, 2 per lane, every wave ----
        {
            int* f0 = flags + (lane << 4);
            int* f1 = flags + ((lane + 64) << 4);
            int v0 = __hip_atomic_load(f0, AQ, SC);
            int v1 = __hip_atomic_load(f1, AQ, SC);
            while (v0 < t || v1 < t) {
                __builtin_amdgcn_s_sleep(1);
                v0 = __hip_atomic_load(f0, AQ, SC);
                v1 = __hip_atomic_load(f1, AQ, SC);
            }
        }
        asm volatile("" ::: "memory");

        // ---- h-part MFMA: A-fragments straight from the MALL ring ----
        {
            const u64* hp = (const u64*)hbuf + (size_t)sr * (NBHH / 4);
            const int hidx = ((row0 + (lane & 15)) << 7) + (kq >> 2);
#pragma unroll
            for (int kt = 0; kt < 16; kt += 2) {
                H8 a0, a1;
                a0.u[0] = __hip_atomic_load(hp + hidx + (kt << 3),           AQ, SC);
                a0.u[1] = __hip_atomic_load(hp + hidx + (kt << 3) + 1,       AQ, SC);
                a1.u[0] = __hip_atomic_load(hp + hidx + ((kt + 1) << 3),     AQ, SC);
                a1.u[1] = __hip_atomic_load(hp + hidx + ((kt + 1) << 3) + 1, AQ, SC);
                acc0 = __builtin_amdgcn_mfma_f32_16x16x32_f16(a0.h, bfrag[16 + kt],     acc0, 0, 0, 0);
                acc1 = __builtin_amdgcn_mfma_f32_16x16x32_f16(a1.h, bfrag[16 + kt + 1], acc1, 0, 0, 0);
            }
        }
        floatx4 acc = acc0 + acc1;

        // ---- gate exchange via LDS ----
        {
            const int ccol = lane & 15;
            const int crow = (lane >> 4) << 2;
#pragma unroll
            for (int v = 0; v < 4; ++v)
                gatebuf[wave * 272 + (crow + v) * 17 + ccol] = acc[v];
        }
        barrier_lgkm();   // (B)

        // ---- epilogue: cell math, packed h store, per-wave publish ----
        float hv;
        {
            const int gidx = tr * 17 + tc;
            float ai = gatebuf[0 * 272 + gidx] + bi;
            float af = gatebuf[1 * 272 + gidx] + bf;
            float ao = gatebuf[2 * 272 + gidx] + bo;
            float ag = gatebuf[3 * 272 + gidx] + bg;
            float ig = 1.f / (1.f + __expf(-ai));
            float fg = 1.f / (1.f + __expf(-af));
            float og = 1.f / (1.f + __expf(-ao));
            float gg = 2.f / (1.f + __expf(-2.f * ag)) - 1.f;
            c_state = fg * c_state + ig * gg;
            hv = og * (2.f / (1.f + __expf(-2.f * c_state)) - 1.f);

            float n1 = __shfl_down(hv, 1);
            float n2 = __shfl_down(hv, 2);
            float n3 = __shfl_down(hv, 3);
            if ((tc & 3) == 0) {
                _Float16 f0 = (_Float16)hv, f1 = (_Float16)n1,
                         f2 = (_Float16)n2, f3 = (_Float16)n3;
                unsigned short s0, s1, s2, s3;
                __builtin_memcpy(&s0, &f0, 2); __builtin_memcpy(&s1, &f1, 2);
                __builtin_memcpy(&s2, &f2, 2); __builtin_memcpy(&s3, &f3, 2);
                u64 v = (u64)s0 | ((u64)s1 << 16) | ((u64)s2 << 32) | ((u64)s3 << 48);
                __hip_atomic_store((u64*)hbuf + (size_t)sw * (NBHH / 4)
                                   + (size_t)gn * 128 + (gh >> 2), v, AQ, SC);
            }
        }
        asm volatile("s_waitcnt vmcnt(0)" ::: "memory");   // own h stores acked
        if (lane == 0) __hip_atomic_store(myflag, t + 1, AQ, SC);

        // ---- off-path: out store; x_{t+1} cvt -> LDS ----
        out[(size_t)gn * (TT * HH) + (size_t)t * HH + gh] = hv;

        if (havex) {
            _Float16* xd = (_Float16*)xbuf[(t + 1) & 1];
            half4 hc;
#pragma unroll
            for (int i = 0; i < 8; ++i) {
                float4 v;
                switch (i) {
                    case 0: v = xv0; break; case 1: v = xv1; break;
                    case 2: v = xv2; break; case 3: v = xv3; break;
                    case 4: v = xv4; break; case 5: v = xv5; break;
                    case 6: v = xv6; break; default: v = xv7; break;
                }
                hc.x = (_Float16)v.x; hc.y = (_Float16)v.y;
                hc.z = (_Float16)v.z; hc.w = (_Float16)v.w;
                *(half4*)&xd[((i << 1) + r2) * XROW + (d4 << 2)] = hc;
            }
        }
        barrier_lgkm();   // (C): xbuf[(t+1)&1] ready, gatebuf reads done
        sr = sw;
    }
}

extern "C" void kernel_launch(void* const* d_in, const int* in_sizes, int n_in,
                              void* d_out, int out_size, void* d_ws, size_t ws_size,
                              hipStream_t stream) {
    const float* x  = (const float*)d_in[0];
    const float* h0 = (const float*)d_in[1];
    const float* Wx = (const float*)d_in[2];
    const float* Wh = (const float*)d_in[3];
    const float* b  = (const float*)d_in[4];
    float* out = (float*)d_out;

    _Float16* hbuf = (_Float16*)d_ws;                      // 3 slots x 64x512 fp16 = 192 KB
    int* done = (int*)((char*)d_ws + 3 * NBHH * sizeof(_Float16));

    init_ws_kernel<<<32, 256, 0, stream>>>(done);          // 8192 flag ints = -1
    lstm_persist<<<dim3(128), dim3(256), 0, stream>>>(x, h0, Wx, Wh, b, out, hbuf, done);
}

// Round 6
// 4898.717 us; speedup vs baseline: 1.8220x; 1.3787x over previous
//
#include <hip/hip_runtime.h>

// LSTM: N=64, T=1024, D=512, H=512. out (N,T,H) fp32 = h_{t+1} for t=0..T-1.
//
// Persistent kernel, 128 wgs x 256 thr. grid = 32 col-groups x 4 row-groups.
// Each wave owns one gate's 16 a-cols, K=1024, fp16 B persistent in VGPRs.
//
// R6: SELF-ANNOUNCING h transport (no flags, no acks).
//   Each h value travels as u32: [fp16 bits << 16 | 16-bit generation tag].
//   Generation u = t+1 goes to ring slot u&1 with tag 0xB000|((u>>1)&1);
//   consecutive writers of a slot alternate tags, so a consumer polling its
//   own data words until tags match gets exactly generation t. This fuses
//   flag-observe + h-load into ONE MALL hop and makes the producer store
//   fire-and-forget: the entire flag publish + vmcnt-ack protocol of R0-R3
//   (2 extra MALL round trips per step, serialized) is deleted.
//   2-slot ring is safe by the dependency chain: writing gen u+2 requires
//   consuming ALL of gen u+1, which requires every wg to have finished
//   step u -- so no reader of gen u can still be active.
//   Numerics: fp16 conversion BEFORE transport, bits carried exactly ->
//   output must be bit-identical to R3 (absmax canary 0.00390625).

#define TT 1024
#define NB 64
#define DD 512
#define HH 512
#define XROW 520           // 512 + 8 pad (elems)
#define NBHH (NB * HH)
#define TTDD (TT * DD)

typedef _Float16 half8 __attribute__((ext_vector_type(8)));
typedef _Float16 half4 __attribute__((ext_vector_type(4)));
typedef float floatx4 __attribute__((ext_vector_type(4)));
typedef unsigned long long u64;
typedef unsigned int u32;
typedef unsigned short u16;

#define AQ __ATOMIC_RELAXED
#define SC __HIP_MEMORY_SCOPE_AGENT

// Fill both ring slots with tag 0xFFFF (matches no generation).
__global__ void init_ws_kernel(u64* hq) {
    hq[blockIdx.x * 256 + threadIdx.x] = 0x0000FFFF0000FFFFULL;  // 32768 u64 = 256 KB
}

__device__ __forceinline__ void barrier_lgkm() {
    asm volatile("s_waitcnt lgkmcnt(0)" ::: "memory");
    __builtin_amdgcn_s_barrier();
    asm volatile("" ::: "memory");
}

#define MFMA16(A, B, C) __builtin_amdgcn_mfma_f32_16x16x32_f16((A), (B), (C), 0, 0, 0)

__global__ __launch_bounds__(256, 1) void lstm_persist(
    const float* __restrict__ x, const float* __restrict__ h0,
    const float* __restrict__ Wx, const float* __restrict__ Wh,
    const float* __restrict__ b, float* __restrict__ out,
    u64* __restrict__ hq)
{
    const int tid  = threadIdx.x;
    const int lane = tid & 63;
    const int wave = tid >> 6;          // 0..3 = gate (i,f,o,g)
    const int cg   = blockIdx.x & 31;   // h-cols cg*16..+15
    const int rg   = blockIdx.x >> 5;   // batch rows rg*16..+15
    const int row0 = rg << 4;

    __shared__ __align__(16) _Float16 xbuf[2][16 * XROW];  // x_t / x_{t+1}
    __shared__ __align__(16) _Float16 hlds[16 * XROW];     // h_t rows (fp16)
    __shared__ float gatebuf[4 * 272];                     // 4 gates x (16 x 17)

    // ---- persistent B fragments: this wave's 16 a-cols, K=1024 ----
    const int bcol = (wave << 9) + (cg << 4) + (lane & 15);
    const int kq   = (lane >> 4) << 3;
    half8 bfrag[32];
#pragma unroll
    for (int kt = 0; kt < 16; ++kt)
#pragma unroll
        for (int j = 0; j < 8; ++j)
            bfrag[kt][j] = (_Float16)Wx[(size_t)((kt << 5) + kq + j) * 2048 + bcol];
#pragma unroll
    for (int kt = 16; kt < 32; ++kt)
#pragma unroll
        for (int j = 0; j < 8; ++j)
            bfrag[kt][j] = (_Float16)Wh[(size_t)((kt << 5) + kq + j - 512) * 2048 + bcol];

    // ---- per-thread output element mapping ----
    const int tr = tid >> 4;            // 0..15 (row of tile; also staging row)
    const int tc = tid & 15;
    const int gn = row0 + tr;           // global batch row
    const int gh = (cg << 4) + tc;      // global h col
    const float bi = b[0 * 512 + gh];
    const float bf = b[1 * 512 + gh];
    const float bo = b[2 * 512 + gh];
    const float bg = b[3 * 512 + gh];
    float c_state = 0.f;

    const int r2 = tid >> 7;            // x-staging helpers
    const int d4 = tid & 127;
    const int arow = (lane & 15) * XROW + kq;

    // ---- prologue: stage x_0 -> xbuf[0]; h0 -> ring slot 0 (gen 0) ----
#pragma unroll
    for (int i = 0; i < 8; ++i) {
        int r = (i << 1) + r2;
        float4 xv = ((const float4*)(x + (size_t)(row0 + r) * TTDD))[d4];
        half4 hc;
        hc.x = (_Float16)xv.x; hc.y = (_Float16)xv.y;
        hc.z = (_Float16)xv.z; hc.w = (_Float16)xv.w;
        *(half4*)&xbuf[0][r * XROW + (d4 << 2)] = hc;
    }
    {
        float hv0 = h0[(size_t)gn * HH + gh];
        float pn  = __shfl_down(hv0, 1);
        if ((tc & 1) == 0) {
            _Float16 f0 = (_Float16)hv0, f1 = (_Float16)pn;
            u16 b0, b1;
            __builtin_memcpy(&b0, &f0, 2); __builtin_memcpy(&b1, &f1, 2);
            const u32 wtag = 0xB000u;   // gen 0: slot 0, (0>>1)&1 = 0
            u32 lo = ((u32)b0 << 16) | wtag;
            u32 hi = ((u32)b1 << 16) | wtag;
            u64 v = (u64)lo | ((u64)hi << 32);
            __hip_atomic_store(hq + (size_t)gn * (HH / 2) + (gh >> 1), v, AQ, SC);
        }
    }
    barrier_lgkm();   // xbuf[0] visible

    for (int t = 0; t < TT; ++t) {
        const bool havex = (t + 1 < TT);

        // ---- 1. issue x_{t+1} loads (latency hides under poll) ----
        float4 xv0, xv1, xv2, xv3, xv4, xv5, xv6, xv7;
        if (havex) {
            const float* xb = x + (size_t)(t + 1) * DD;
            xv0 = ((const float4*)(xb + (size_t)(row0 + 0  + r2) * TTDD))[d4];
            xv1 = ((const float4*)(xb + (size_t)(row0 + 2  + r2) * TTDD))[d4];
            xv2 = ((const float4*)(xb + (size_t)(row0 + 4  + r2) * TTDD))[d4];
            xv3 = ((const float4*)(xb + (size_t)(row0 + 6  + r2) * TTDD))[d4];
            xv4 = ((const float4*)(xb + (size_t)(row0 + 8  + r2) * TTDD))[d4];
            xv5 = ((const float4*)(xb + (size_t)(row0 + 10 + r2) * TTDD))[d4];
            xv6 = ((const float4*)(xb + (size_t)(row0 + 12 + r2) * TTDD))[d4];
            xv7 = ((const float4*)(xb + (size_t)(row0 + 14 + r2) * TTDD))[d4];
        }

        // ---- 2. x-part MFMA from xbuf[t&1] (LDS only) ----
        floatx4 acc0 = {0.f, 0.f, 0.f, 0.f};
        floatx4 acc1 = {0.f, 0.f, 0.f, 0.f};
        const _Float16* xa = xbuf[t & 1];
#pragma unroll
        for (int kt = 0; kt < 16; kt += 2) {
            half8 a0 = *(const half8*)&xa[arow + (kt << 5)];
            half8 a1 = *(const half8*)&xa[arow + ((kt + 1) << 5)];
            acc0 = MFMA16(a0, bfrag[kt],     acc0);
            acc1 = MFMA16(a1, bfrag[kt + 1], acc1);
        }

        // ---- 3. poll+stage h_t: each thread spins on ITS 16 tagged words ----
        {
            const u32 want = 0xB000u | ((u32)(t >> 1) & 1u);
            const u64* src = hq + (size_t)(t & 1) * (NBHH / 2)
                           + (size_t)gn * (HH / 2) + ((size_t)tc << 4);
            u64 w[16];
            bool all;
            do {
#pragma unroll
                for (int j = 0; j < 16; ++j)
                    w[j] = __hip_atomic_load(src + j, AQ, SC);
                all = true;
#pragma unroll
                for (int j = 0; j < 16; ++j) {
                    u32 lo = (u32)w[j], hi = (u32)(w[j] >> 32);
                    all = all && ((lo & 0xFFFFu) == want)
                              && ((hi & 0xFFFFu) == want);
                }
            } while (!all);
            u32* dst = (u32*)&hlds[tr * XROW + (tc << 5)];
#pragma unroll
            for (int j = 0; j < 16; ++j) {
                u32 lo = (u32)w[j] >> 16;
                u32 hi = (u32)(w[j] >> 32) >> 16;
                dst[j] = lo | (hi << 16);     // 2x fp16, cols tc*32+2j, +1
            }
        }
        barrier_lgkm();   // A: h tile staged

        // ---- 4. h-part MFMA ----
#pragma unroll
        for (int kt = 0; kt < 16; kt += 2) {
            half8 a0 = *(const half8*)&hlds[arow + (kt << 5)];
            half8 a1 = *(const half8*)&hlds[arow + ((kt + 1) << 5)];
            acc0 = MFMA16(a0, bfrag[16 + kt],     acc0);
            acc1 = MFMA16(a1, bfrag[16 + kt + 1], acc1);
        }
        floatx4 acc = acc0 + acc1;

        // ---- 5. gate exchange through LDS ----
        {
            const int ccol = lane & 15;
            const int crow = (lane >> 4) << 2;
#pragma unroll
            for (int v = 0; v < 4; ++v)
                gatebuf[wave * 272 + (crow + v) * 17 + ccol] = acc[v];
        }
        barrier_lgkm();   // B

        // ---- 6. cell math; tagged h-store (fire-and-forget); out store ----
        {
            const int gidx = tr * 17 + tc;
            float ai = gatebuf[0 * 272 + gidx] + bi;
            float af = gatebuf[1 * 272 + gidx] + bf;
            float ao = gatebuf[2 * 272 + gidx] + bo;
            float ag = gatebuf[3 * 272 + gidx] + bg;
            float ig = 1.f / (1.f + __expf(-ai));
            float fg = 1.f / (1.f + __expf(-af));
            float og = 1.f / (1.f + __expf(-ao));
            float gg = 2.f / (1.f + __expf(-2.f * ag)) - 1.f;   // tanh
            c_state = fg * c_state + ig * gg;
            float hv = og * (2.f / (1.f + __expf(-2.f * c_state)) - 1.f);

            float pn = __shfl_down(hv, 1);
            if ((tc & 1) == 0) {
                _Float16 f0 = (_Float16)hv, f1 = (_Float16)pn;
                u16 b0, b1;
                __builtin_memcpy(&b0, &f0, 2); __builtin_memcpy(&b1, &f1, 2);
                const u32 wtag = 0xB000u | ((u32)((t + 1) >> 1) & 1u);
                u32 lo = ((u32)b0 << 16) | wtag;
                u32 hi = ((u32)b1 << 16) | wtag;
                u64 v = (u64)lo | ((u64)hi << 32);
                __hip_atomic_store(hq + (size_t)(((t + 1) & 1)) * (NBHH / 2)
                                   + (size_t)gn * (HH / 2) + (gh >> 1), v, AQ, SC);
            }
            out[(size_t)gn * (TT * HH) + (size_t)t * HH + gh] = hv;
        }

        // ---- 7. cvt x_{t+1} -> alternate LDS x-half ----
        if (havex) {
            _Float16* xd = (_Float16*)xbuf[(t + 1) & 1];
            half4 hc;
#pragma unroll
            for (int i = 0; i < 8; ++i) {
                float4 v;
                switch (i) {
                    case 0: v = xv0; break; case 1: v = xv1; break;
                    case 2: v = xv2; break; case 3: v = xv3; break;
                    case 4: v = xv4; break; case 5: v = xv5; break;
                    case 6: v = xv6; break; default: v = xv7; break;
                }
                hc.x = (_Float16)v.x; hc.y = (_Float16)v.y;
                hc.z = (_Float16)v.z; hc.w = (_Float16)v.w;
                *(half4*)&xd[((i << 1) + r2) * XROW + (d4 << 2)] = hc;
            }
        }
        barrier_lgkm();   // C: xbuf[(t+1)&1] ready; gatebuf/hlds reads done
    }
}

extern "C" void kernel_launch(void* const* d_in, const int* in_sizes, int n_in,
                              void* d_out, int out_size, void* d_ws, size_t ws_size,
                              hipStream_t stream) {
    const float* x  = (const float*)d_in[0];
    const float* h0 = (const float*)d_in[1];
    const float* Wx = (const float*)d_in[2];
    const float* Wh = (const float*)d_in[3];
    const float* b  = (const float*)d_in[4];
    float* out = (float*)d_out;

    u64* hq = (u64*)d_ws;   // 2 slots x 64 x 512 x u32 = 256 KB

    init_ws_kernel<<<128, 256, 0, stream>>>(hq);
    lstm_persist<<<dim3(128), dim3(256), 0, stream>>>(x, h0, Wx, Wh, b, out, hq);
}

// Round 7
// 3090.548 us; speedup vs baseline: 2.8880x; 1.5851x over previous
//
#include <hip/hip_runtime.h>

// LSTM: N=64, T=1024, D=512, H=512. out (N,T,H) fp32 = h_{t+1} for t=0..T-1.
//
// Persistent kernel, 128 wgs x 256 thr. grid = 32 col-groups x 4 row-groups.
// Each wave owns one gate's 16 a-cols, K=1024, fp16 B persistent in VGPRs.
// h transport: self-announcing tagged u32 words (R6) -- no flags, no acks.
//
// R7 changes (vmcnt hygiene + barrier/bank reduction):
//   1. Wave specialization: waves 0,1 are pure pollers (vm queue holds ONLY
//      poll loads + own fire-forget h-stores, whose ack hides under the
//      first poll iteration). Waves 2,3 own the x pipeline (16 float4 in
//      flight across the step) and ALL out HBM stores (rows 0-7 handed
//      via LDS houts, written one step late). The poll's vmcnt(0) no
//      longer drains HBM x-loads (~600cy/step saved on the wait path).
//   2. Two barriers per step (A: h staged, B: gatebuf + xbuf ready).
//      Barrier C removed: x-cvt moved before B; every LDS buffer's
//      write->read pair is separated by A or B (checked per-buffer).
//   3. Bank-clean h staging: pollers poll strided words (idx pc+8j) so
//      LDS stage writes land 2-3-way (was 8-way with 64B blocks).

#define TT 1024
#define NB 64
#define DD 512
#define HH 512
#define XROW 520           // 512 + 8 pad (elems): MFMA b128 reads 2-way (free)
#define NBHH (NB * HH)
#define TTDD (TT * DD)

typedef _Float16 half8 __attribute__((ext_vector_type(8)));
typedef _Float16 half4 __attribute__((ext_vector_type(4)));
typedef float floatx4 __attribute__((ext_vector_type(4)));
typedef unsigned long long u64;
typedef unsigned int u32;
typedef unsigned short u16;

#define AQ __ATOMIC_RELAXED
#define SC __HIP_MEMORY_SCOPE_AGENT

// Fill both ring slots with tag 0xFFFF (matches no generation).
__global__ void init_ws_kernel(u64* hq) {
    hq[blockIdx.x * 256 + threadIdx.x] = 0x0000FFFF0000FFFFULL;  // 32768 u64
}

__device__ __forceinline__ void barrier_lgkm() {
    asm volatile("s_waitcnt lgkmcnt(0)" ::: "memory");
    __builtin_amdgcn_s_barrier();
    asm volatile("" ::: "memory");
}

#define MFMA16(A, B, C) __builtin_amdgcn_mfma_f32_16x16x32_f16((A), (B), (C), 0, 0, 0)

__global__ __launch_bounds__(256, 1) void lstm_persist(
    const float* __restrict__ x, const float* __restrict__ h0,
    const float* __restrict__ Wx, const float* __restrict__ Wh,
    const float* __restrict__ b, float* __restrict__ out,
    u64* __restrict__ hq)
{
    const int tid  = threadIdx.x;
    const int lane = tid & 63;
    const int wave = tid >> 6;          // 0..3 = gate (i,f,o,g)
    const int cg   = blockIdx.x & 31;   // h-cols cg*16..+15
    const int rg   = blockIdx.x >> 5;   // batch rows rg*16..+15
    const int row0 = rg << 4;

    __shared__ __align__(16) _Float16 xbuf[2][16 * XROW];  // x_t / x_{t+1}
    __shared__ __align__(16) _Float16 hlds[16 * XROW];     // h_t rows (fp16)
    __shared__ float gatebuf[4 * 272];                     // 4 gates x (16 x 17)
    __shared__ float houts[2][128];                        // rows 0-7 hv handoff

    // ---- persistent B fragments: this wave's 16 a-cols, K=1024 ----
    const int bcol = (wave << 9) + (cg << 4) + (lane & 15);
    const int kq   = (lane >> 4) << 3;
    half8 bfrag[32];
#pragma unroll
    for (int kt = 0; kt < 16; ++kt)
#pragma unroll
        for (int j = 0; j < 8; ++j)
            bfrag[kt][j] = (_Float16)Wx[(size_t)((kt << 5) + kq + j) * 2048 + bcol];
#pragma unroll
    for (int kt = 16; kt < 32; ++kt)
#pragma unroll
        for (int j = 0; j < 8; ++j)
            bfrag[kt][j] = (_Float16)Wh[(size_t)((kt << 5) + kq + j - 512) * 2048 + bcol];

    // ---- per-thread output element mapping ----
    const int tr = tid >> 4;            // 0..15
    const int tc = tid & 15;
    const int gn = row0 + tr;           // global batch row
    const int gh = (cg << 4) + tc;      // global h col
    const float bi = b[0 * 512 + gh];
    const float bf = b[1 * 512 + gh];
    const float bo = b[2 * 512 + gh];
    const float bg = b[3 * 512 + gh];
    float c_state = 0.f;

    const int r2 = tid >> 7;            // prologue x-staging helpers
    const int d4 = tid & 127;
    const int arow = (lane & 15) * XROW + kq;

    // w23 x-pipeline mapping: 128 threads, 16 rows x 8 thr, 16 float4 each
    const int lt  = tid & 127;
    const int xr  = lt >> 3;            // 0..15
    const int xc8 = lt & 7;             // 0..7

    // ---- prologue: stage x_0 -> xbuf[0]; h0 -> ring slot 0 (gen 0) ----
#pragma unroll
    for (int i = 0; i < 8; ++i) {
        int r = (i << 1) + r2;
        float4 xv = ((const float4*)(x + (size_t)(row0 + r) * TTDD))[d4];
        half4 hc;
        hc.x = (_Float16)xv.x; hc.y = (_Float16)xv.y;
        hc.z = (_Float16)xv.z; hc.w = (_Float16)xv.w;
        *(half4*)&xbuf[0][r * XROW + (d4 << 2)] = hc;
    }
    {
        float hv0 = h0[(size_t)gn * HH + gh];
        float pn  = __shfl_down(hv0, 1);
        if ((tc & 1) == 0) {
            _Float16 f0 = (_Float16)hv0, f1 = (_Float16)pn;
            u16 b0, b1;
            __builtin_memcpy(&b0, &f0, 2); __builtin_memcpy(&b1, &f1, 2);
            const u32 wtag = 0xB000u;   // gen 0: slot 0, tag bit 0
            u32 lo = ((u32)b0 << 16) | wtag;
            u32 hi = ((u32)b1 << 16) | wtag;
            u64 v = (u64)lo | ((u64)hi << 32);
            __hip_atomic_store(hq + (size_t)gn * 256 + (gh >> 1), v, AQ, SC);
        }
    }
    barrier_lgkm();   // xbuf[0] visible

    for (int t = 0; t < TT; ++t) {
        const bool havex = (t + 1 < TT);

        // ---- 1. w23: issue x_{t+1} loads (held in regs through the step) ----
        float4 xvv[16];
        if (wave >= 2 && havex) {
            const float4* xsrc = (const float4*)(x + (size_t)(row0 + xr) * TTDD
                                                 + (size_t)(t + 1) * DD);
#pragma unroll
            for (int j = 0; j < 16; ++j)
                xvv[j] = xsrc[xc8 + (j << 3)];
        }

        // ---- 2. x-part MFMA from xbuf[t&1] (LDS only, all waves) ----
        floatx4 acc0 = {0.f, 0.f, 0.f, 0.f};
        floatx4 acc1 = {0.f, 0.f, 0.f, 0.f};
        const _Float16* xa = xbuf[t & 1];
#pragma unroll
        for (int kt = 0; kt < 16; kt += 2) {
            half8 a0 = *(const half8*)&xa[arow + (kt << 5)];
            half8 a1 = *(const half8*)&xa[arow + ((kt + 1) << 5)];
            acc0 = MFMA16(a0, bfrag[kt],     acc0);
            acc1 = MFMA16(a1, bfrag[kt + 1], acc1);
        }

        // ---- 3. w01: poll own 32 tagged u64 words; stage to hlds ----
        if (wave < 2) {
            const int pr = tid >> 3;    // 0..15 (tile row)
            const int pc = tid & 7;     // 0..7
            const u64 wantp = ((u64)(0xB000u | ((u32)(t >> 1) & 1u)))
                              * 0x0000000100000001ULL;
            const u64* src = hq + (size_t)(t & 1) * (NBHH / 2)
                           + (size_t)(row0 + pr) * 256 + pc;
            u64 w[32];
            bool ok;
            do {
#pragma unroll
                for (int j = 0; j < 32; ++j)
                    w[j] = __hip_atomic_load(src + (j << 3), AQ, SC);
                u64 chk = 0;
#pragma unroll
                for (int j = 0; j < 32; ++j)
                    chk |= (w[j] ^ wantp) & 0x0000FFFF0000FFFFULL;
                ok = (chk == 0);
            } while (!ok);
            u32* dst = (u32*)hlds + pr * 260 + pc;
#pragma unroll
            for (int j = 0; j < 32; ++j) {
                u32 lo = (u32)w[j] >> 16;
                u32 hi = (u32)(w[j] >> 32) & 0xFFFF0000u;
                dst[j << 3] = lo | hi;      // cols 2W, 2W+1 (W = pc+8j)
            }
        }
        barrier_lgkm();   // A: h tile staged

        // ---- 4. h-part MFMA (all waves) ----
#pragma unroll
        for (int kt = 0; kt < 16; kt += 2) {
            half8 a0 = *(const half8*)&hlds[arow + (kt << 5)];
            half8 a1 = *(const half8*)&hlds[arow + ((kt + 1) << 5)];
            acc0 = MFMA16(a0, bfrag[16 + kt],     acc0);
            acc1 = MFMA16(a1, bfrag[16 + kt + 1], acc1);
        }
        floatx4 acc = acc0 + acc1;

        // ---- 5. gate exchange through LDS ----
        {
            const int ccol = lane & 15;
            const int crow = (lane >> 4) << 2;
#pragma unroll
            for (int v = 0; v < 4; ++v)
                gatebuf[wave * 272 + (crow + v) * 17 + ccol] = acc[v];
        }

        // ---- 6. w23: handed out-stores (t-1, rows 0-7); cvt x_{t+1} -> LDS ----
        if (wave >= 2) {
            if (t > 0) {
                float hvp = houts[(t - 1) & 1][lt];
                out[(size_t)(row0 + (lt >> 4)) * (TT * HH) + (size_t)(t - 1) * HH
                    + (cg << 4) + (lt & 15)] = hvp;
            }
            if (havex) {
                _Float16* xd = xbuf[(t + 1) & 1] + xr * XROW;
                half4 hc;
#pragma unroll
                for (int j = 0; j < 16; ++j) {
                    float4 v = xvv[j];
                    hc.x = (_Float16)v.x; hc.y = (_Float16)v.y;
                    hc.z = (_Float16)v.z; hc.w = (_Float16)v.w;
                    *(half4*)&xd[(xc8 + (j << 3)) << 2] = hc;
                }
            }
        }
        barrier_lgkm();   // B: gatebuf + xbuf[(t+1)&1] ready

        // ---- 7. epilogue (all threads): cell math; tagged h-store ----
        {
            const int gidx = tr * 17 + tc;
            float ai = gatebuf[0 * 272 + gidx] + bi;
            float af = gatebuf[1 * 272 + gidx] + bf;
            float ao = gatebuf[2 * 272 + gidx] + bo;
            float ag = gatebuf[3 * 272 + gidx] + bg;
            float ig = 1.f / (1.f + __expf(-ai));
            float fg = 1.f / (1.f + __expf(-af));
            float og = 1.f / (1.f + __expf(-ao));
            float gg = 2.f / (1.f + __expf(-2.f * ag)) - 1.f;   // tanh
            c_state = fg * c_state + ig * gg;
            float hv = og * (2.f / (1.f + __expf(-2.f * c_state)) - 1.f);

            float pn = __shfl_down(hv, 1);
            if ((tc & 1) == 0) {
                _Float16 f0 = (_Float16)hv, f1 = (_Float16)pn;
                u16 b0, b1;
                __builtin_memcpy(&b0, &f0, 2); __builtin_memcpy(&b1, &f1, 2);
                const u32 wtag = 0xB000u | ((u32)((t + 1) >> 1) & 1u);
                u32 lo = ((u32)b0 << 16) | wtag;
                u32 hi = ((u32)b1 << 16) | wtag;
                u64 v = (u64)lo | ((u64)hi << 32);
                __hip_atomic_store(hq + (size_t)((t + 1) & 1) * (NBHH / 2)
                                   + (size_t)gn * 256 + (gh >> 1), v, AQ, SC);
            }
            // out: w01 hand over via LDS (w23 stores next step); w23 direct.
            if (wave < 2) houts[t & 1][tid] = hv;
            else out[(size_t)gn * (TT * HH) + (size_t)t * HH + gh] = hv;
        }
        // no barrier here: houts(t) read at t+1 after A; gatebuf rewritten
        // at t+1 after A; hlds rewritten pre-A(t+1) but read only pre-B(t). 
    }

    // ---- tail: flush handed rows for t = TT-1 ----
    barrier_lgkm();
    if (wave >= 2) {
        float hvp = houts[(TT - 1) & 1][lt];
        out[(size_t)(row0 + (lt >> 4)) * (TT * HH) + (size_t)(TT - 1) * HH
            + (cg << 4) + (lt & 15)] = hvp;
    }
}

extern "C" void kernel_launch(void* const* d_in, const int* in_sizes, int n_in,
                              void* d_out, int out_size, void* d_ws, size_t ws_size,
                              hipStream_t stream) {
    const float* x  = (const float*)d_in[0];
    const float* h0 = (const float*)d_in[1];
    const float* Wx = (const float*)d_in[2];
    const float* Wh = (const float*)d_in[3];
    const float* b  = (const float*)d_in[4];
    float* out = (float*)d_out;

    u64* hq = (u64*)d_ws;   // 2 slots x 64 x 512 x u32 = 256 KB

    init_ws_kernel<<<128, 256, 0, stream>>>(hq);
    lstm_persist<<<dim3(128), dim3(256), 0, stream>>>(x, h0, Wx, Wh, b, out, hq);
}